// Round 1
// baseline (399.476 us; speedup 1.0000x reference)
//
#include <hip/hip_runtime.h>
#include <math.h>

#define DIM 128

typedef __attribute__((ext_vector_type(8))) short bf16x8;
typedef __attribute__((ext_vector_type(4))) float f32x4;

__device__ __forceinline__ ushort f2bf(float f) {  // RTNE
  unsigned u = __float_as_uint(f);
  return (ushort)((u + 0x7FFFu + ((u >> 16) & 1u)) >> 16);
}
__device__ __forceinline__ float bf2f(ushort h) {
  return __uint_as_float(((unsigned)h) << 16);
}

// ---------------- K1: hist_rank || GEMM1 (x@W1l, x@W1r) || wsplit(W2), interleaved ----------------
// Linearity: mean_agg(x)@W1l == mean_agg(x@W1l), so layer-1 GEMMs have no graph
// dependency and hide under the 71us atomic-stream shadow of the histogram.
__global__ __launch_bounds__(256) void prep2_kernel(
    const int* __restrict__ dst, unsigned* __restrict__ deg, unsigned* __restrict__ rank, int E,
    const float* __restrict__ x,
    const float* __restrict__ W1l, const float* __restrict__ W1r,
    ushort* __restrict__ xl, ushort* __restrict__ xr,
    const float* __restrict__ W2l, const float* __restrict__ W2r,
    ushort* __restrict__ tabs, int H, int G1, int N) {
  __shared__ ushort As[128 * 64];  // 16 KB
  __shared__ ushort Bs[128 * 64];  // 16 KB
  const int tid = threadIdx.x;
  const int bid = blockIdx.x;
  const int r5 = bid % 5;
  const int q5 = bid / 5;

  if (r5 != 4) {  // histogram role: 4/5 of blocks
    int hid = q5 * 4 + r5;
    if (hid < H) {
      int gid = hid * 256 + tid;
      if (gid < E) rank[gid] = atomicAdd(&deg[dst[gid]], 1u);
    }
    return;
  }
  int aid = q5;
  if (aid >= 2 * G1) {  // wsplit role: transpose+cast W2l/W2r to bf16 tabs
    int aid2 = aid - 2 * G1;
    if (aid2 < 128) {
      int m = aid2 >> 6;
      const float* W = m ? W2r : W2l;
      ushort* Ht = tabs + (size_t)m * 16384;
      int idx = (aid2 & 63) * 256 + tid;
      int k = idx >> 7, n = idx & 127;
      Ht[n * DIM + k] = f2bf(W[idx]);
    }
    return;
  }

  // ---- GEMM1 role: out = x @ W (fp32 inputs, bf16 output), 128-row tile ----
  const int m = aid / G1;  // 0: W1l -> xl, 1: W1r -> xr
  const int tile = aid % G1;
  const int bm = tile * 128;
  const float* W = m ? W1r : W1l;
  ushort* out = m ? xr : xl;

  const int wave = tid >> 6;
  const int lane = tid & 63;
  const int l15 = lane & 15;
  const int quad = lane >> 4;
  const int wm = wave >> 1;
  const int wn = wave & 1;

  f32x4 acc[4][4];
#pragma unroll
  for (int i = 0; i < 4; ++i)
#pragma unroll
    for (int j = 0; j < 4; ++j) acc[i][j] = (f32x4){0.f, 0.f, 0.f, 0.f};

  for (int g = 0; g < 2; ++g) {
    const int kt = g << 6;
    __syncthreads();
    // stage A: x fp32 [128 rows][64 k] -> bf16 swizzled
#pragma unroll
    for (int c = 0; c < 8; ++c) {
      int flat = c * 256 + tid;  // float4 index, 0..2047
      int row = flat >> 4;
      int q4 = flat & 15;
      int grow = bm + row;
      if (grow >= N) grow = N - 1;
      float4 v = *(const float4*)(x + (size_t)grow * DIM + kt + q4 * 4);
      int kb = q4 >> 1, ki = (q4 & 1) << 2;
      uint2 pk;
      pk.x = (unsigned)f2bf(v.x) | ((unsigned)f2bf(v.y) << 16);
      pk.y = (unsigned)f2bf(v.z) | ((unsigned)f2bf(v.w) << 16);
      *(uint2*)(&As[row * 64 + ((kb ^ (row & 7)) << 3) + ki]) = pk;
    }
    // stage B: W fp32 [k][n] -> Bs[n][k swizzled] (transpose during store)
#pragma unroll
    for (int c = 0; c < 32; ++c) {
      int idx = c * 256 + tid;  // 0..8191
      int kk = idx >> 7, n = idx & 127;
      Bs[n * 64 + (((kk >> 3) ^ (n & 7)) << 3) + (kk & 7)] =
          f2bf(W[(size_t)(kt + kk) * DIM + n]);
    }
    __syncthreads();
#pragma unroll
    for (int ks = 0; ks < 2; ++ks) {
      bf16x8 af[4], bfr[4];
      int kg = (ks << 2) + quad;
#pragma unroll
      for (int i = 0; i < 4; ++i) {
        int ar = (wm << 6) + (i << 4) + l15;
        af[i] = *(const bf16x8*)(&As[ar * 64 + ((kg ^ (ar & 7)) << 3)]);
        int br = (wn << 6) + (i << 4) + l15;
        bfr[i] = *(const bf16x8*)(&Bs[br * 64 + ((kg ^ (br & 7)) << 3)]);
      }
#pragma unroll
      for (int i = 0; i < 4; ++i)
#pragma unroll
        for (int j = 0; j < 4; ++j)
          acc[i][j] = __builtin_amdgcn_mfma_f32_16x16x32_bf16(af[i], bfr[j], acc[i][j], 0, 0, 0);
    }
  }

  // epilogue: raw bf16 store (no bias, no relu)
#pragma unroll
  for (int i = 0; i < 4; ++i) {
#pragma unroll
    for (int r = 0; r < 4; ++r) {
      const int rowl = (wm << 6) + (i << 4) + (quad << 2) + r;
      const int grow = bm + rowl;
      if (grow < N) {
#pragma unroll
        for (int j = 0; j < 4; ++j) {
          int col = (wn << 6) + (j << 4) + l15;
          out[(size_t)grow * DIM + col] = f2bf(acc[i][j][r]);
        }
      }
    }
  }
}

// ---------------- two-level exclusive scan over deg (+ fused dinv) ----------------
__global__ __launch_bounds__(256) void scan_block_kernel(const unsigned* __restrict__ deg,
                                                         unsigned* __restrict__ excl,
                                                         unsigned* __restrict__ partial,
                                                         float* __restrict__ dinv, int N) {
  __shared__ unsigned s[256];
  int i = blockIdx.x * 256 + threadIdx.x;
  unsigned v = (i < N) ? deg[i] : 0u;
  if (i < N) dinv[i] = 1.0f / fmaxf((float)v, 1.0f);
  s[threadIdx.x] = v;
  __syncthreads();
#pragma unroll
  for (int d = 1; d < 256; d <<= 1) {
    unsigned t = (threadIdx.x >= d) ? s[threadIdx.x - d] : 0u;
    __syncthreads();
    s[threadIdx.x] += t;
    __syncthreads();
  }
  if (i < N) excl[i] = s[threadIdx.x] - v;
  if (threadIdx.x == 255) partial[blockIdx.x] = s[255];
}

__global__ __launch_bounds__(256) void scan_partials_kernel(unsigned* __restrict__ partial, int B) {
  __shared__ unsigned s[256];
  __shared__ unsigned carry;
  if (threadIdx.x == 0) carry = 0u;
  __syncthreads();
  for (int base = 0; base < B; base += 256) {
    int i = base + threadIdx.x;
    unsigned v = (i < B) ? partial[i] : 0u;
    s[threadIdx.x] = v;
    __syncthreads();
#pragma unroll
    for (int d = 1; d < 256; d <<= 1) {
      unsigned t = (threadIdx.x >= d) ? s[threadIdx.x - d] : 0u;
      __syncthreads();
      s[threadIdx.x] += t;
      __syncthreads();
    }
    if (i < B) partial[i] = carry + s[threadIdx.x] - v;
    __syncthreads();
    if (threadIdx.x == 0) carry += s[255];
    __syncthreads();
  }
}

__global__ __launch_bounds__(256) void add_offsets_kernel(const unsigned* __restrict__ excl,
                                                          const unsigned* __restrict__ partial,
                                                          unsigned* __restrict__ off, int N, int E) {
  int i = blockIdx.x * 256 + threadIdx.x;
  if (i < N) off[i] = excl[i] + partial[i >> 8];
  if (i == N) off[N] = (unsigned)E;
}

// ---------------- CSR fill: atomic-free ----------------
__global__ __launch_bounds__(256) void csr_fill_kernel(const int* __restrict__ src,
                                                       const int* __restrict__ dst,
                                                       const unsigned* __restrict__ rank,
                                                       const unsigned* __restrict__ off,
                                                       int* __restrict__ csr_src, int E) {
  int e = blockIdx.x * 256 + threadIdx.x;
  if (e >= E) return;
  csr_src[off[dst[e]] + rank[e]] = src[e];
}

// ---------------- gather body macro: wave-per-node aggregation into acc[8] ----------------
#define GATHER_BODY(TABLE)                                                       \
  const int node = (blockIdx.x * 256 + threadIdx.x) >> 6;                        \
  if (node >= N) return;                                                         \
  const int lane = threadIdx.x & 63;                                             \
  const int eslot = lane >> 4;                                                   \
  const int col = lane & 15;                                                     \
  const unsigned beg = off[node], end = off[node + 1];                           \
  const ushort* fbase = (TABLE) + col * 8;                                       \
  float acc[8];                                                                  \
  _Pragma("unroll") for (int t = 0; t < 8; ++t) acc[t] = 0.f;                    \
  auto accum = [&](int4 v) {                                                     \
    unsigned w0 = (unsigned)v.x, w1 = (unsigned)v.y;                             \
    unsigned w2 = (unsigned)v.z, w3 = (unsigned)v.w;                             \
    acc[0] += __uint_as_float(w0 << 16);                                         \
    acc[1] += __uint_as_float(w0 & 0xFFFF0000u);                                 \
    acc[2] += __uint_as_float(w1 << 16);                                         \
    acc[3] += __uint_as_float(w1 & 0xFFFF0000u);                                 \
    acc[4] += __uint_as_float(w2 << 16);                                         \
    acc[5] += __uint_as_float(w2 & 0xFFFF0000u);                                 \
    acc[6] += __uint_as_float(w3 << 16);                                         \
    acc[7] += __uint_as_float(w3 & 0xFFFF0000u);                                 \
  };                                                                             \
  unsigned base = beg;                                                           \
  for (; base + 16 <= end; base += 16) {                                         \
    int s0 = csr_src[base + eslot];                                              \
    int s1 = csr_src[base + 4 + eslot];                                          \
    int s2 = csr_src[base + 8 + eslot];                                          \
    int s3 = csr_src[base + 12 + eslot];                                         \
    int4 v0 = *(const int4*)(fbase + (size_t)s0 * DIM);                          \
    int4 v1 = *(const int4*)(fbase + (size_t)s1 * DIM);                          \
    int4 v2 = *(const int4*)(fbase + (size_t)s2 * DIM);                          \
    int4 v3 = *(const int4*)(fbase + (size_t)s3 * DIM);                          \
    accum(v0); accum(v1); accum(v2); accum(v3);                                  \
  }                                                                              \
  for (; base + 8 <= end; base += 8) {                                           \
    int s0 = csr_src[base + eslot];                                              \
    int s1 = csr_src[base + 4 + eslot];                                          \
    int4 v0 = *(const int4*)(fbase + (size_t)s0 * DIM);                          \
    int4 v1 = *(const int4*)(fbase + (size_t)s1 * DIM);                          \
    accum(v0); accum(v1);                                                        \
  }                                                                              \
  for (unsigned e = base + eslot; e < end; e += 4) {                             \
    int s = csr_src[e];                                                          \
    int4 v = *(const int4*)(fbase + (size_t)s * DIM);                            \
    accum(v);                                                                    \
  }                                                                              \
  _Pragma("unroll") for (int t = 0; t < 8; ++t) {                                \
    acc[t] += __shfl_xor(acc[t], 32, 64);                                        \
    acc[t] += __shfl_xor(acc[t], 16, 64);                                        \
  }

// ---------------- gather1: agg(xl), fused layer-1 epilogue -> h1 ----------------
__global__ __launch_bounds__(256) void gather1_kernel(
    const ushort* __restrict__ xl, const int* __restrict__ csr_src,
    const unsigned* __restrict__ off, const float* __restrict__ dinv,
    const ushort* __restrict__ xr, const float* __restrict__ b1,
    ushort* __restrict__ h1, int N) {
  GATHER_BODY(xl)
  if (eslot == 0) {
    float di = dinv[node];
    int4 xv = *(const int4*)(xr + (size_t)node * DIM + col * 8);
    float4 ba = *(const float4*)(b1 + col * 8);
    float4 bb = *(const float4*)(b1 + col * 8 + 4);
    unsigned w0 = (unsigned)xv.x, w1 = (unsigned)xv.y;
    unsigned w2 = (unsigned)xv.z, w3 = (unsigned)xv.w;
    float h[8];
    h[0] = fmaxf(acc[0] * di + __uint_as_float(w0 << 16) + ba.x, 0.f);
    h[1] = fmaxf(acc[1] * di + __uint_as_float(w0 & 0xFFFF0000u) + ba.y, 0.f);
    h[2] = fmaxf(acc[2] * di + __uint_as_float(w1 << 16) + ba.z, 0.f);
    h[3] = fmaxf(acc[3] * di + __uint_as_float(w1 & 0xFFFF0000u) + ba.w, 0.f);
    h[4] = fmaxf(acc[4] * di + __uint_as_float(w2 << 16) + bb.x, 0.f);
    h[5] = fmaxf(acc[5] * di + __uint_as_float(w2 & 0xFFFF0000u) + bb.y, 0.f);
    h[6] = fmaxf(acc[6] * di + __uint_as_float(w3 << 16) + bb.z, 0.f);
    h[7] = fmaxf(acc[7] * di + __uint_as_float(w3 & 0xFFFF0000u) + bb.w, 0.f);
    unsigned ph[4];
#pragma unroll
    for (int t = 0; t < 4; ++t)
      ph[t] = (unsigned)f2bf(h[2 * t]) | ((unsigned)f2bf(h[2 * t + 1]) << 16);
    *(int4*)(h1 + (size_t)node * DIM + col * 8) =
        make_int4((int)ph[0], (int)ph[1], (int)ph[2], (int)ph[3]);
  }
}

// ---------------- K5: h1 @ [W2l | W2r] -> h1l, h1r(+b2), bf16 tabs B ----------------
__global__ __launch_bounds__(256) void gemm2_kernel(
    const ushort* __restrict__ h1, const ushort* __restrict__ tabs,
    const float* __restrict__ b2, ushort* __restrict__ h1l, ushort* __restrict__ h1r,
    int G1, int N) {
  __shared__ ushort As[128 * 64];
  __shared__ ushort Bs[128 * 64];
  const int tid = threadIdx.x;
  const int m = blockIdx.x / G1;  // 0: W2l -> h1l, 1: W2r -> h1r (+b2)
  const int tile = blockIdx.x % G1;
  const int bm = tile * 128;
  const ushort* Wt = tabs + (size_t)m * 16384;
  ushort* out = m ? h1r : h1l;

  const int wave = tid >> 6;
  const int lane = tid & 63;
  const int l15 = lane & 15;
  const int quad = lane >> 4;
  const int wm = wave >> 1;
  const int wn = wave & 1;

  f32x4 acc[4][4];
#pragma unroll
  for (int i = 0; i < 4; ++i)
#pragma unroll
    for (int j = 0; j < 4; ++j) acc[i][j] = (f32x4){0.f, 0.f, 0.f, 0.f};

  for (int g = 0; g < 2; ++g) {
    const int kt = g << 6;
    __syncthreads();
#pragma unroll
    for (int c = 0; c < 4; ++c) {
      int flat = c * 256 + tid;
      int row = flat >> 3;
      int kg = flat & 7;
      int swz = (kg ^ (row & 7)) << 3;
      int grow = bm + row;
      if (grow >= N) grow = N - 1;
      *(int4*)(&As[row * 64 + swz]) = *(const int4*)(h1 + (size_t)grow * DIM + kt + kg * 8);
      *(int4*)(&Bs[row * 64 + swz]) = *(const int4*)(Wt + (size_t)row * DIM + kt + kg * 8);
    }
    __syncthreads();
#pragma unroll
    for (int ks = 0; ks < 2; ++ks) {
      bf16x8 af[4], bfr[4];
      int kg = (ks << 2) + quad;
#pragma unroll
      for (int i = 0; i < 4; ++i) {
        int ar = (wm << 6) + (i << 4) + l15;
        af[i] = *(const bf16x8*)(&As[ar * 64 + ((kg ^ (ar & 7)) << 3)]);
        int br = (wn << 6) + (i << 4) + l15;
        bfr[i] = *(const bf16x8*)(&Bs[br * 64 + ((kg ^ (br & 7)) << 3)]);
      }
#pragma unroll
      for (int i = 0; i < 4; ++i)
#pragma unroll
        for (int j = 0; j < 4; ++j)
          acc[i][j] = __builtin_amdgcn_mfma_f32_16x16x32_bf16(af[i], bfr[j], acc[i][j], 0, 0, 0);
    }
  }

  float bv[4];
#pragma unroll
  for (int j = 0; j < 4; ++j)
    bv[j] = m ? b2[(wn << 6) + (j << 4) + l15] : 0.f;

#pragma unroll
  for (int i = 0; i < 4; ++i) {
#pragma unroll
    for (int r = 0; r < 4; ++r) {
      const int rowl = (wm << 6) + (i << 4) + (quad << 2) + r;
      const int grow = bm + rowl;
      if (grow < N) {
#pragma unroll
        for (int j = 0; j < 4; ++j) {
          int col = (wn << 6) + (j << 4) + l15;
          out[(size_t)grow * DIM + col] = f2bf(acc[i][j][r] + bv[j]);  // raw, no relu
        }
      }
    }
  }
}

// ---------------- gather2: agg(h1l), fused h2=relu(.)+ lin3 dot -> y[N][4] ----------------
__global__ __launch_bounds__(256) void gather2_kernel(
    const ushort* __restrict__ h1l, const int* __restrict__ csr_src,
    const unsigned* __restrict__ off, const float* __restrict__ dinv,
    const ushort* __restrict__ h1r, const float* __restrict__ W3l,
    const float* __restrict__ W3r, float* __restrict__ y, int N) {
  GATHER_BODY(h1l)
  if (eslot == 0) {
    float di = dinv[node];
    int4 xv = *(const int4*)(h1r + (size_t)node * DIM + col * 8);
    unsigned w0 = (unsigned)xv.x, w1 = (unsigned)xv.y;
    unsigned w2 = (unsigned)xv.z, w3 = (unsigned)xv.w;
    float h[8];
    h[0] = fmaxf(acc[0] * di + __uint_as_float(w0 << 16), 0.f);
    h[1] = fmaxf(acc[1] * di + __uint_as_float(w0 & 0xFFFF0000u), 0.f);
    h[2] = fmaxf(acc[2] * di + __uint_as_float(w1 << 16), 0.f);
    h[3] = fmaxf(acc[3] * di + __uint_as_float(w1 & 0xFFFF0000u), 0.f);
    h[4] = fmaxf(acc[4] * di + __uint_as_float(w2 << 16), 0.f);
    h[5] = fmaxf(acc[5] * di + __uint_as_float(w2 & 0xFFFF0000u), 0.f);
    h[6] = fmaxf(acc[6] * di + __uint_as_float(w3 << 16), 0.f);
    h[7] = fmaxf(acc[7] * di + __uint_as_float(w3 & 0xFFFF0000u), 0.f);
    const int d0 = col * 8;
    float y0 = 0.f, y1 = 0.f, y2 = 0.f, y3 = 0.f;
#pragma unroll
    for (int t = 0; t < 8; t += 2) {  // W3 rows (d0+t, d0+t+1); 16B-aligned float4
      float4 wl = *(const float4*)(W3l + (size_t)(d0 + t) * 2);
      float4 wr = *(const float4*)(W3r + (size_t)(d0 + t) * 2);
      y0 += h[t] * wl.x + h[t + 1] * wl.z;
      y1 += h[t] * wl.y + h[t + 1] * wl.w;
      y2 += h[t] * wr.x + h[t + 1] * wr.z;
      y3 += h[t] * wr.y + h[t + 1] * wr.w;
    }
#pragma unroll
    for (int o = 1; o < 16; o <<= 1) {  // reduce across lanes 0..15 (all active)
      y0 += __shfl_xor(y0, o, 64);
      y1 += __shfl_xor(y1, o, 64);
      y2 += __shfl_xor(y2, o, 64);
      y3 += __shfl_xor(y3, o, 64);
    }
    if (lane == 0) *(float4*)(y + (size_t)node * 4) = make_float4(y0, y1, y2, y3);
  }
}

// ---------------- layer 3: 2-dim CSR gather + bias + relu + log_softmax ----------------
__global__ __launch_bounds__(256) void final3_kernel(const float* __restrict__ y,
                                                     const int* __restrict__ csr_src,
                                                     const unsigned* __restrict__ off,
                                                     const float* __restrict__ dinv,
                                                     const float* __restrict__ b3,
                                                     float* __restrict__ out, int N) {
  int n = blockIdx.x * 256 + threadIdx.x;
  if (n >= N) return;
  unsigned beg = off[n], end = off[n + 1];
  float s0 = 0.f, s1 = 0.f;
  for (unsigned e = beg; e < end; ++e) {
    int s = csr_src[e];
    float2 v = *reinterpret_cast<const float2*>(&y[(size_t)s * 4]);
    s0 += v.x; s1 += v.y;
  }
  float di = dinv[n];
  float o0 = fmaxf(s0 * di + y[(size_t)n * 4 + 2] + b3[0], 0.f);
  float o1 = fmaxf(s1 * di + y[(size_t)n * 4 + 3] + b3[1], 0.f);
  float m = fmaxf(o0, o1);
  float l = m + logf(expf(o0 - m) + expf(o1 - m));
  out[n * 2 + 0] = o0 - l;
  out[n * 2 + 1] = o1 - l;
}

extern "C" void kernel_launch(void* const* d_in, const int* in_sizes, int n_in,
                              void* d_out, int out_size, void* d_ws, size_t ws_size,
                              hipStream_t stream) {
  const float* x   = (const float*)d_in[0];
  const int*   ei  = (const int*)d_in[1];
  const float* W1l = (const float*)d_in[2];
  const float* W1r = (const float*)d_in[3];
  const float* b1  = (const float*)d_in[4];
  const float* W2l = (const float*)d_in[5];
  const float* W2r = (const float*)d_in[6];
  const float* b2  = (const float*)d_in[7];
  const float* W3l = (const float*)d_in[8];
  const float* W3r = (const float*)d_in[9];
  const float* b3  = (const float*)d_in[10];

  const int N = in_sizes[0] / DIM;  // 100000
  const int E = in_sizes[1] / 2;    // 1600000
  const int* src = ei;
  const int* dst = ei + E;
  const int B = (N + 255) / 256;

  char* ws = (char*)d_ws;
  size_t off_b = 0;
  auto alloc = [&](size_t bytes) {
    void* p = ws + off_b;
    off_b = (off_b + bytes + 255) & ~(size_t)255;
    return p;
  };
  unsigned* deg     = (unsigned*)alloc((size_t)N * 4);
  unsigned* excl    = (unsigned*)alloc((size_t)N * 4);
  unsigned* partial = (unsigned*)alloc((size_t)B * 4);
  unsigned* offs    = (unsigned*)alloc((size_t)(N + 1) * 4);
  unsigned* rank    = (unsigned*)alloc((size_t)E * 4);
  int*      csr_src = (int*)alloc((size_t)E * 4);
  float*    dinv    = (float*)alloc((size_t)N * 4);
  ushort*   xl      = (ushort*)alloc((size_t)N * DIM * 2);
  ushort*   xr      = (ushort*)alloc((size_t)N * DIM * 2);
  ushort*   h1      = (ushort*)alloc((size_t)N * DIM * 2);
  ushort*   tabs    = (ushort*)alloc((size_t)2 * 16384 * 2);
  float*    y       = (float*)alloc((size_t)N * 4 * 4);
  // buffer reuse: h1l overwrites xl, h1r overwrites xr (both dead after gather1;
  // gemm2 reads only h1, writes tile-local rows -> no intra-kernel hazard)
  ushort* h1l = xl;
  ushort* h1r = xr;

  const int H  = (E + 255) / 256;   // 6250 hist blocks
  const int G1 = (N + 127) / 128;   // 782 GEMM tiles per operand
  const int AUX = 2 * G1 + 128;     // gemm + wsplit blocks
  const int HQ = (H + 3) / 4;
  const int P = (AUX > HQ) ? AUX : HQ;

  hipMemsetAsync(deg, 0, (size_t)N * 4, stream);
  // K1: hist atomics (shadow) || layer-1 GEMMs || W2 wsplit
  prep2_kernel<<<5 * P, 256, 0, stream>>>(dst, deg, rank, E, x, W1l, W1r, xl, xr,
                                          W2l, W2r, tabs, H, G1, N);

  scan_block_kernel<<<B, 256, 0, stream>>>(deg, excl, partial, dinv, N);
  scan_partials_kernel<<<1, 256, 0, stream>>>(partial, B);
  add_offsets_kernel<<<(N + 256) / 256, 256, 0, stream>>>(excl, partial, offs, N, E);
  csr_fill_kernel<<<(E + 255) / 256, 256, 0, stream>>>(src, dst, rank, offs, csr_src, E);

  const int gather_grid = (N + 3) / 4;  // one wave per node
  // layer 1: h1 = relu(mean_agg(xl) + xr + b1)
  gather1_kernel<<<gather_grid, 256, 0, stream>>>(xl, csr_src, offs, dinv, xr, b1, h1, N);
  // layer 2 GEMMs: h1l = h1@W2l, h1r = h1@W2r + b2
  gemm2_kernel<<<2 * G1, 256, 0, stream>>>(h1, tabs, b2, h1l, h1r, G1, N);
  // layer 2 epilogue + lin3: h2 = relu(mean_agg(h1l) + h1r); y = h2@[W3l|W3r]
  gather2_kernel<<<gather_grid, 256, 0, stream>>>(h1l, csr_src, offs, dinv, h1r, W3l, W3r, y, N);
  // layer 3
  final3_kernel<<<(N + 255) / 256, 256, 0, stream>>>(y, csr_src, offs, dinv, b3, (float*)d_out, N);
}